// Round 1
// baseline (151.606 us; speedup 1.0000x reference)
//
#include <hip/hip_runtime.h>

#define BATCH   256
#define NFEAT   20000
#define KSEL    256
#define NSAMP   8

// Map float bits to an unsigned key with the same total order as float compare
// (for non-NaN inputs): larger float <=> larger key.
__device__ __forceinline__ unsigned fmap(float f) {
    unsigned u = __float_as_uint(f);
    return (u & 0x80000000u) ? ~u : (u | 0x80000000u);
}

// One block (256 threads) per row. Radix-select the K-th largest key, then
// find the cutoff index among ties (jax.lax.top_k includes lowest indices
// first). Writes {thr_key, cutoff_idx} per row.
__global__ __launch_bounds__(256) void topk_select(const float* __restrict__ logits,
                                                   uint2* __restrict__ rowinfo) {
    const int b   = blockIdx.x;
    const int tid = threadIdx.x;
    const float* row = logits + (size_t)b * NFEAT;

    __shared__ unsigned hist[256];
    __shared__ unsigned s_digit, s_want;

    unsigned prefix = 0;
    int want = KSEL;   // how many elements still to select inside the matching set

    for (int pass = 0; pass < 4; ++pass) {
        const int shift = 24 - 8 * pass;
        hist[tid] = 0;
        __syncthreads();
        for (int i = tid; i < NFEAT; i += 256) {
            unsigned k = fmap(row[i]);
            bool match = (pass == 0) || ((k >> (shift + 8)) == prefix);
            if (match) atomicAdd(&hist[(k >> shift) & 255u], 1u);
        }
        __syncthreads();
        if (tid == 0) {
            int w = want;
            int d = 255;
            for (; d > 0; --d) {
                int c = (int)hist[d];
                if (c >= w) break;
                w -= c;
            }
            s_digit = (unsigned)d;
            s_want  = (unsigned)w;
        }
        __syncthreads();
        prefix = (prefix << 8) | s_digit;
        want   = (int)s_want;
    }

    const unsigned thr = prefix;   // K-th largest key
    const int budget   = want;     // number of ==thr elements to include (>=1)

    // Ordered scan over the row: find the (budget)-th element equal to thr.
    __shared__ int s_running;
    __shared__ int s_cutoff;
    __shared__ int s_wavecnt[4];
    if (tid == 0) { s_running = 0; s_cutoff = NFEAT; }
    __syncthreads();

    const int wave = tid >> 6;
    const int lane = tid & 63;
    for (int base = 0; base < NFEAT; base += 256) {
        const int i = base + tid;
        const bool eq = (i < NFEAT) && (fmap(row[i]) == thr);
        const unsigned long long bal = __ballot(eq);
        if (lane == 0) s_wavecnt[wave] = __popcll(bal);
        __syncthreads();
        int waveoff = 0;
        for (int w = 0; w < wave; ++w) waveoff += s_wavecnt[w];
        const int rank = s_running + waveoff +
                         __popcll(bal & ((lane == 0) ? 0ull : ((1ull << lane) - 1ull)));
        if (eq && rank == budget - 1) s_cutoff = i;
        __syncthreads();
        if (tid == 0)
            s_running += s_wavecnt[0] + s_wavecnt[1] + s_wavecnt[2] + s_wavecnt[3];
        __syncthreads();
        if (s_running >= budget) break;   // uniform across block
    }

    if (tid == 0) {
        rowinfo[b] = make_uint2(thr, (unsigned)s_cutoff);
    }
}

// Each thread: one float4 of logits -> 4 mask values -> write to all 8 samples.
__global__ __launch_bounds__(256) void write_out(const float* __restrict__ logits,
                                                 const uint2* __restrict__ rowinfo,
                                                 float* __restrict__ out) {
    const int b = blockIdx.y;
    const int q = blockIdx.x * 256 + threadIdx.x;   // index over N/4
    if (q >= NFEAT / 4) return;

    const uint2 info   = rowinfo[b];
    const unsigned thr = info.x;
    const int cutoff   = (int)info.y;

    const int n = q * 4;
    const float4 v = *reinterpret_cast<const float4*>(logits + (size_t)b * NFEAT + n);

    float4 m;
    {
        const float* vf = &v.x;
        float*       mf = &m.x;
#pragma unroll
        for (int j = 0; j < 4; ++j) {
            const unsigned k = fmap(vf[j]);
            mf[j] = (k > thr || (k == thr && (n + j) <= cutoff)) ? 1.0f : 0.0f;
        }
    }

#pragma unroll
    for (int s = 0; s < NSAMP; ++s) {
        *reinterpret_cast<float4*>(out + ((size_t)s * BATCH + b) * NFEAT + n) = m;
    }
}

extern "C" void kernel_launch(void* const* d_in, const int* in_sizes, int n_in,
                              void* d_out, int out_size, void* d_ws, size_t ws_size,
                              hipStream_t stream) {
    const float* logits = (const float*)d_in[0];
    float* out = (float*)d_out;
    uint2* rowinfo = (uint2*)d_ws;   // 256 * 8 B = 2 KB

    topk_select<<<BATCH, 256, 0, stream>>>(logits, rowinfo);

    dim3 grid((NFEAT / 4 + 255) / 256, BATCH);
    write_out<<<grid, 256, 0, stream>>>(logits, rowinfo, out);
}

// Round 2
// 43.958 us; speedup vs baseline: 3.4489x; 3.4489x over previous
//
#include <hip/hip_runtime.h>

#define BATCH   256
#define NFEAT   20000
#define NVEC    (NFEAT / 4)
#define KSEL    256
#define NSAMP   8
#define CAP     4096

typedef unsigned long long u64;

// Map float bits to unsigned key with same total order as float compare.
__device__ __forceinline__ unsigned fmap(float f) {
    unsigned u = __float_as_uint(f);
    return (u & 0x80000000u) ? ~u : (u | 0x80000000u);
}

// Wave 0 (64 lanes) scans hist[nbins-1 .. 0] top-down, finds bin where the
// cumulative count (from the top) reaches w. Writes bin -> *s_d and the
// remaining want inside that bin -> *s_w.
__device__ __forceinline__ void select_bin_wave0(const unsigned* hist, int nbins, int w,
                                                 int* s_d, int* s_w, int lane) {
    for (int base = nbins - 1; base >= 0; base -= 64) {
        int bin = base - lane;                       // lane 0 = highest bin
        unsigned c = (bin >= 0) ? hist[bin] : 0u;
        unsigned p = c;                              // inclusive scan from lane 0
#pragma unroll
        for (int off = 1; off < 64; off <<= 1) {
            unsigned t = __shfl_up(p, off);
            if (lane >= off) p += t;
        }
        unsigned long long m = __ballot(p >= (unsigned)w);
        if (m) {
            int l = __ffsll(m) - 1;                  // first lane (highest bin) crossing
            if (lane == l) { *s_d = bin; *s_w = w - (int)(p - c); }
            return;
        }
        w -= (int)__shfl(p, 63);                     // subtract whole-chunk sum
    }
    if (lane == 0) { *s_d = 0; *s_w = 1; }           // unreachable safety
}

// One 1024-thread block per row. Exact top-K threshold as a 64-bit composite
// (key<<32 | ~idx): element selected iff composite >= thr. Composites are
// globally distinct, so tie-break = lowest index, matching jax.lax.top_k.
__global__ __launch_bounds__(1024) void topk_select(const float* __restrict__ logits,
                                                    u64* __restrict__ rowthr) {
    const int b = blockIdx.x, tid = threadIdx.x;
    const int lane = tid & 63, wave = tid >> 6;
    const float4* row4 = (const float4*)(logits + (size_t)b * NFEAT);

    __shared__ unsigned hist[4096];
    __shared__ u64 cand[CAP];
    __shared__ int s_d, s_w;
    __shared__ unsigned s_cnt;
    __shared__ u64 s_thr;
    __shared__ int s_run, s_cut, s_wc[16];

    // ---- Pass 1: 12-bit histogram over key[31:20] ----
    for (int i = tid; i < 4096; i += 1024) hist[i] = 0;
    __syncthreads();
    for (int i = tid; i < NVEC; i += 1024) {
        float4 v = row4[i];
        atomicAdd(&hist[fmap(v.x) >> 20], 1u);
        atomicAdd(&hist[fmap(v.y) >> 20], 1u);
        atomicAdd(&hist[fmap(v.z) >> 20], 1u);
        atomicAdd(&hist[fmap(v.w) >> 20], 1u);
    }
    __syncthreads();
    if (wave == 0) select_bin_wave0(hist, 4096, KSEL, &s_d, &s_w, lane);
    __syncthreads();

    unsigned keypref = (unsigned)s_d;
    int w = s_w;
    int shift = 20;
    unsigned C;

    // ---- Pass 2: gather candidates matching key prefix (refine if overflow) ----
    for (;;) {
        if (tid == 0) s_cnt = 0;
        __syncthreads();
        for (int i = tid; i < NVEC; i += 1024) {
            float4 v = row4[i];
            const int base = i * 4;
            unsigned k;
            k = fmap(v.x); if ((k >> shift) == keypref) { unsigned p = atomicAdd(&s_cnt, 1u); if (p < CAP) cand[p] = ((u64)k << 32) | (unsigned)~(base + 0); }
            k = fmap(v.y); if ((k >> shift) == keypref) { unsigned p = atomicAdd(&s_cnt, 1u); if (p < CAP) cand[p] = ((u64)k << 32) | (unsigned)~(base + 1); }
            k = fmap(v.z); if ((k >> shift) == keypref) { unsigned p = atomicAdd(&s_cnt, 1u); if (p < CAP) cand[p] = ((u64)k << 32) | (unsigned)~(base + 2); }
            k = fmap(v.w); if ((k >> shift) == keypref) { unsigned p = atomicAdd(&s_cnt, 1u); if (p < CAP) cand[p] = ((u64)k << 32) | (unsigned)~(base + 3); }
        }
        __syncthreads();
        C = s_cnt;
        if (C <= CAP || shift == 0) break;

        // overflow (unreachable for this input): refine key prefix by 12/8 bits
        const int nb = (shift >= 12) ? 12 : shift;
        const int nsh = shift - nb;
        const unsigned mask = (1u << nb) - 1u;
        for (int i = tid; i < (1 << nb); i += 1024) hist[i] = 0;
        __syncthreads();
        for (int i = tid; i < NVEC; i += 1024) {
            float4 v = row4[i];
            unsigned k;
            k = fmap(v.x); if ((k >> shift) == keypref) atomicAdd(&hist[(k >> nsh) & mask], 1u);
            k = fmap(v.y); if ((k >> shift) == keypref) atomicAdd(&hist[(k >> nsh) & mask], 1u);
            k = fmap(v.z); if ((k >> shift) == keypref) atomicAdd(&hist[(k >> nsh) & mask], 1u);
            k = fmap(v.w); if ((k >> shift) == keypref) atomicAdd(&hist[(k >> nsh) & mask], 1u);
        }
        __syncthreads();
        if (wave == 0) select_bin_wave0(hist, 1 << nb, w, &s_d, &s_w, lane);
        __syncthreads();
        keypref = (keypref << nb) | (unsigned)s_d;
        w = s_w;
        shift = nsh;
    }

    if (C <= CAP) {
        // ---- In-LDS radix select: w-th largest composite among C candidates ----
        u64 pfx = keypref;
        int pshift = 32 + shift;       // candidates share composite >> pshift == pfx
        bool done = false;
        while (!done) {
            const int nb = (pshift >= 8) ? 8 : pshift;
            const int nsh = pshift - nb;
            const unsigned mask = (1u << nb) - 1u;
            for (int i = tid; i < (1 << nb); i += 1024) hist[i] = 0;
            __syncthreads();
            for (int i = tid; i < (int)C; i += 1024) {
                u64 c = cand[i];
                if ((c >> pshift) == pfx) atomicAdd(&hist[(unsigned)(c >> nsh) & mask], 1u);
            }
            __syncthreads();
            if (wave == 0) select_bin_wave0(hist, 1 << nb, w, &s_d, &s_w, lane);
            __syncthreads();
            const unsigned cnt = hist[s_d];
            pfx = (pfx << nb) | (unsigned)s_d;
            w = s_w;
            pshift = nsh;
            if (cnt == 1u || pshift == 0) {
                if (cnt == 1u && pshift > 0) {
                    for (int i = tid; i < (int)C; i += 1024) {
                        u64 c = cand[i];
                        if ((c >> pshift) == pfx) s_thr = c;   // exactly one writer
                    }
                } else if (tid == 0) {
                    s_thr = pfx;                               // fully resolved
                }
                done = true;
            }
            __syncthreads();
        }
    } else {
        // shift==0, full key resolved, >CAP exact duplicates (unreachable):
        // find w-th smallest index among exact-key matches via ordered ballot scan.
        if (tid == 0) { s_run = 0; s_cut = 0; }
        __syncthreads();
        const float* row = logits + (size_t)b * NFEAT;
        for (int base = 0; base < NFEAT; base += 1024) {
            const int i = base + tid;
            const bool eq = (i < NFEAT) && (fmap(row[i]) == keypref);
            const unsigned long long bal = __ballot(eq);
            if (lane == 0) s_wc[wave] = __popcll(bal);
            __syncthreads();
            int off = s_run;
            for (int x = 0; x < wave; ++x) off += s_wc[x];
            const int rank = off + __popcll(bal & ((lane == 0) ? 0ull : ((1ull << lane) - 1ull)));
            if (eq && rank == w - 1) s_cut = i;
            __syncthreads();
            if (tid == 0) { int t = 0; for (int x = 0; x < 16; ++x) t += s_wc[x]; s_run += t; }
            __syncthreads();
            if (s_run >= w) break;
        }
        if (tid == 0) s_thr = ((u64)keypref << 32) | (unsigned)~s_cut;
        __syncthreads();
    }

    if (tid == 0) rowthr[b] = s_thr;
}

// Each thread: one float4 of logits -> 4 mask values -> write to all 8 samples.
__global__ __launch_bounds__(256) void write_out(const float* __restrict__ logits,
                                                 const u64* __restrict__ rowthr,
                                                 float* __restrict__ out) {
    const int b = blockIdx.y;
    const int q = blockIdx.x * 256 + threadIdx.x;   // index over N/4
    if (q >= NVEC) return;

    const u64 thr = rowthr[b];
    const int n = q * 4;
    const float4 v = *reinterpret_cast<const float4*>(logits + (size_t)b * NFEAT + n);

    float4 m;
    {
        const float* vf = &v.x;
        float*       mf = &m.x;
#pragma unroll
        for (int j = 0; j < 4; ++j) {
            const u64 comp = ((u64)fmap(vf[j]) << 32) | (unsigned)~(n + j);
            mf[j] = (comp >= thr) ? 1.0f : 0.0f;
        }
    }

#pragma unroll
    for (int s = 0; s < NSAMP; ++s) {
        *reinterpret_cast<float4*>(out + ((size_t)s * BATCH + b) * NFEAT + n) = m;
    }
}

extern "C" void kernel_launch(void* const* d_in, const int* in_sizes, int n_in,
                              void* d_out, int out_size, void* d_ws, size_t ws_size,
                              hipStream_t stream) {
    const float* logits = (const float*)d_in[0];
    float* out = (float*)d_out;
    u64* rowthr = (u64*)d_ws;   // 256 * 8 B = 2 KB

    topk_select<<<BATCH, 1024, 0, stream>>>(logits, rowthr);

    dim3 grid((NVEC + 255) / 256, BATCH);
    write_out<<<grid, 256, 0, stream>>>(logits, rowthr, out);
}